// Round 8
// baseline (40.628 us; speedup 1.0000x reference)
//
#include <hip/hip_runtime.h>
#include <hip/hip_bf16.h>

// InvButterflyLayer via MFMA (bf16 in, fp32 accum). B=256, MID=16384, C=16.
// Live cone: level lvl needs t < 2^(8-lvl); lvl0 t<256 -> x[0:8224).
//
// Formulation: each level/node is [rows x 32] * [32 x 16], K = 2 parents x 16
// ch (k2 = 2c + parity). One 16x16x32 MFMA per 16-row tile; D packs into 2 b32
// bf16-pair writes at [row2][2d+(r&1)] building the next level's A. Weights
// staged transposed [node][d][k2]. fsw() = XOR swizzle on LDS offsets.
//
// R8 vs R7: HW bf16 cvt (compiler fuses to v_cvt_pk_bf16_f32); dense+recombine
// moved to kernel C (FE converted ONCE per n8, was 64x redundant per-block);
// B ends at lvl8 -> S8 (d_ws+4MB) via coalesced copy; B LDS 69.5->61KB.

#define OUT_HALF 2097152

typedef __attribute__((ext_vector_type(4))) float f32x4;
typedef __attribute__((ext_vector_type(8))) short s16x8;

__device__ __forceinline__ uint fsw(uint a) {
    return a ^ ((((a >> 6) ^ (a >> 8)) & 3u) << 4);
}
__device__ __forceinline__ ushort bfr(float f) {   // HW RNE cvt
    __hip_bfloat16 h = __float2bfloat16(f);
    union { __hip_bfloat16 h; ushort u; } cv; cv.h = h; return cv.u;
}
__device__ __forceinline__ uint pk(float a, float b) {
    return (uint)bfr(a) | ((uint)bfr(b) << 16);
}

// Generic tree level: A[plane p][16-row tiles] x W[child] -> next A.
__device__ __forceinline__ void tree_level(
    char* smb, const int lane, const int wave,
    uint AOff, uint NOff, int lgR, int lgNP, int nTiles,
    uint WOff, int wnb, uint LBOff, int bnb)
{
    const int m  = lane & 15;
    const int kg = lane >> 4;
    const int lgTPP = lgR - 4;
    for (int at = wave; at < nTiles; at += 4) {
        const int p  = at >> lgTPP;
        const int tc = at & ((1 << lgTPP) - 1);
        const int np = p & ((1 << lgNP) - 1);
        const int ii = p >> lgNP;
        s16x8 af = *(const s16x8*)(smb + AOff + (p << (lgR + 6)) +
                                   fsw((uint)((tc * 16 + m) * 64 + kg * 16)));
#pragma unroll
        for (int sib = 0; sib < 2; sib++) {
            const int nl = 2 * np + sib;
            s16x8 bf = *(const s16x8*)(smb + WOff +
                         fsw((uint)((wnb + nl) * 1024 + m * 64 + kg * 16)));
            float bv = *(const float*)(smb + LBOff + ((bnb + nl) * 16 + m) * 4);
            f32x4 acc = {bv, bv, bv, bv};
            acc = __builtin_amdgcn_mfma_f32_16x16x32_bf16(af, bf, acc, 0, 0, 0);
            const int p2 = (ii << (lgNP + 1)) + nl;
            const uint wb = NOff + (p2 << (lgR + 5));
            const int r2 = tc * 8 + kg * 2;
            *(uint*)(smb + wb + fsw((uint)(r2 * 64 + m * 4))) =
                pk(fmaxf(acc.x, 0.f), fmaxf(acc.y, 0.f));
            *(uint*)(smb + wb + fsw((uint)((r2 + 1) * 64 + m * 4))) =
                pk(fmaxf(acc.z, 0.f), fmaxf(acc.w, 0.f));
        }
    }
}

// LDS map A (bytes): X0@0[8256] X1@8256[8256] | A2@0[8192] A3@8256[8192]
//                    A1@16512[8192] W@24704[14336] BT0@39040[2048] LB@41088[960]
__global__ __launch_bounds__(256, 3)
void ibf_A(const float* __restrict__ in_data, const float* __restrict__ mid_dense,
           const float* __restrict__ in_filter, const float* __restrict__ in_bias,
           const float* __restrict__ filters, const float* __restrict__ biases,
           uint* __restrict__ S3)
{
    __shared__ __align__(16) char smb[42048];
    const int tid = threadIdx.x, lane = tid & 63, wave = tid >> 6;
    const int b = blockIdx.x, th = blockIdx.y;

    // stage x = in_data*mid (m in [th*4096, th*4096+4128)) -> X0/X1 bf16
    {
        const float4* inb = (const float4*)in_data + (size_t)b * 8192 + th * 2048;
        const float4* mdb = (const float4*)mid_dense + th * 2048;
        for (int mp = tid; mp < 2064; mp += 256) {
            float4 iv = inb[mp], mv = mdb[mp];
            *(uint*)(smb + 0    + fsw((uint)(mp * 4))) = pk(iv.x * mv.x, iv.z * mv.z);
            *(uint*)(smb + 8256 + fsw((uint)(mp * 4))) = pk(iv.y * mv.y, iv.w * mv.w);
        }
    }
    // stage lvl1-3 weights: W[nidx][d][k2=2c+par] bf16
    for (int t = tid; t < 3584; t += 256) {
        int nidx = t >> 8, r = t & 255, d = r & 15, c = r >> 4;
        int lvl = (nidx < 2) ? 1 : ((nidx < 6) ? 2 : 3);
        int n = nidx - ((1 << lvl) - 2);
        const float* src = filters + (size_t)(lvl - 1) * 131072 + n * 512 + c * 16 + d;
        *(uint*)(smb + 24704 + fsw((uint)(nidx * 1024 + d * 64 + c * 4))) = pk(src[0], src[256]);
    }
    // stage in_filter: BT0[c][w] bf16
    for (int t = tid; t < 512; t += 256) {
        int c = t >> 5, w2 = t & 31;
        *(uint*)(smb + 39040 + fsw((uint)(c * 128 + w2 * 4))) =
            pk(in_filter[(2 * w2) * 16 + c], in_filter[(2 * w2 + 1) * 16 + c]);
    }
    // stage biases f32: nidx 0..13 tree, 224.. = in_bias
    if (tid < 240) {
        float v;
        if (tid < 224) {
            int nidx = tid >> 4;
            int lvl = (nidx < 2) ? 1 : ((nidx < 6) ? 2 : 3);
            int n = nidx - ((1 << lvl) - 2);
            v = biases[(size_t)(lvl - 1) * 4096 + n * 16 + (tid & 15)];
        } else v = in_bias[tid - 224];
        *(float*)(smb + 41088 + tid * 4) = v;
    }
    __syncthreads();

    // lvl0: A[t][w=64] (x windows) x BT0 -> A1
    {
        const int m = lane & 15, kg = lane >> 4;
        s16x8 b0 = *(const s16x8*)(smb + 39040 + fsw((uint)(m * 128 + kg * 16)));
        s16x8 b1 = *(const s16x8*)(smb + 39040 + fsw((uint)(m * 128 + 64 + kg * 16)));
        float bv = *(const float*)(smb + 41088 + (224 + m) * 4);
        for (int at = wave; at < 16; at += 4) {
            int i = at >> 3, tc = at & 7;
            uint xb = i ? 8256u : 0u;
            s16x8 a0 = *(const s16x8*)(smb + xb + fsw((uint)((tc * 16 + m) * 64 + kg * 16)));
            s16x8 a1 = *(const s16x8*)(smb + xb + fsw((uint)((tc * 16 + m) * 64 + 64 + kg * 16)));
            f32x4 acc = {bv, bv, bv, bv};
            acc = __builtin_amdgcn_mfma_f32_16x16x32_bf16(a0, b0, acc, 0, 0, 0);
            acc = __builtin_amdgcn_mfma_f32_16x16x32_bf16(a1, b1, acc, 0, 0, 0);
            uint wb = 16512u + (uint)i * 4096u;
            int r2 = tc * 8 + kg * 2;
            *(uint*)(smb + wb + fsw((uint)(r2 * 64 + m * 4))) =
                pk(fmaxf(acc.x, 0.f), fmaxf(acc.y, 0.f));
            *(uint*)(smb + wb + fsw((uint)((r2 + 1) * 64 + m * 4))) =
                pk(fmaxf(acc.z, 0.f), fmaxf(acc.w, 0.f));
        }
    }
    __syncthreads();
    tree_level(smb, lane, wave, 16512, 0,    6, 0, 8, 24704, 0, 41088, 0);  // lvl1
    __syncthreads();
    tree_level(smb, lane, wave, 0,     8256, 5, 1, 8, 24704, 2, 41088, 2);  // lvl2
    __syncthreads();
    // lvl3 -> S3 global, bf16 pairs
    {
        const int m = lane & 63 & 15, kg = (lane & 63) >> 4;
        for (int at = wave; at < 8; at += 4) {
            int np = at & 3, i = at >> 2;
            s16x8 af = *(const s16x8*)(smb + 8256 + (at << 10) + fsw((uint)(m * 64 + kg * 16)));
#pragma unroll
            for (int sib = 0; sib < 2; sib++) {
                int n3 = 2 * np + sib;
                s16x8 bf = *(const s16x8*)(smb + 24704 +
                             fsw((uint)((6 + n3) * 1024 + m * 64 + kg * 16)));
                float bv = *(const float*)(smb + 41088 + ((6 + n3) * 16 + m) * 4);
                f32x4 acc = {bv, bv, bv, bv};
                acc = __builtin_amdgcn_mfma_f32_16x16x32_bf16(af, bf, acc, 0, 0, 0);
                int bi = 2 * b + i;
                int t4 = th * 8 + kg * 2;
                uint idx = ((uint)(n3 * 512 + bi) * 16 + t4) * 16 + m;
                S3[idx]      = pk(fmaxf(acc.x, 0.f), fmaxf(acc.y, 0.f));
                S3[idx + 16] = pk(fmaxf(acc.z, 0.f), fmaxf(acc.w, 0.f));
            }
        }
    }
}

// LDS map B (bytes): P0@0[8192] P1@8192[8192] AF@16384[8192] W@24576[32768] LB@57344[3968]
__global__ __launch_bounds__(256, 2)
void ibf_B(const float* __restrict__ filters, const float* __restrict__ biases,
           const uint* __restrict__ S3, char* __restrict__ S8)
{
    __shared__ __align__(16) char smb[61312];
    const int tid = threadIdx.x, lane = tid & 63, wave = tid >> 6;
    const int n3 = blockIdx.x, chunk = blockIdx.y;

    // stage A4 from S3 (byte-image copy with dest swizzle)
    {
        const char* src = (const char*)S3 + ((size_t)n3 * 512 + chunk * 8) * 1024;
        for (int ci = tid; ci < 512; ci += 256)
            *(float4*)(smb + fsw((uint)(ci * 16))) = *(const float4*)(src + ci * 16);
    }
    // stage biases (62 nodes, level-concat)
    for (int t = tid; t < 992; t += 256) {
        int nidx = t >> 4, q = nidx + 2;
        int l3 = 31 - __clz(q);
        int nl = q - (1 << l3);
        int gn = (n3 << l3) + nl;
        *(float*)(smb + 57344 + t * 4) = biases[(size_t)(l3 + 2) * 4096 + gn * 16 + (t & 15)];
    }
    auto stage_w = [&](int l3) {
        int NL = 1 << l3;
        const float* fb = filters + (size_t)(l3 + 2) * 131072;
        for (int t = tid; t < NL * 256; t += 256) {
            int nl = t >> 8, r = t & 255, d = r & 15, c = r >> 4;
            const float* src = fb + (size_t)((n3 << l3) + nl) * 512 + c * 16 + d;
            *(uint*)(smb + 24576 + fsw((uint)(nl * 1024 + d * 64 + c * 4))) = pk(src[0], src[256]);
        }
    };
    stage_w(1);
    __syncthreads();
    tree_level(smb, lane, wave, 0,    8192, 7, 0, 8, 24576, 0, 57344, 0);   // lvl4
    __syncthreads();
    stage_w(2);
    __syncthreads();
    tree_level(smb, lane, wave, 8192, 0,    6, 1, 8, 24576, 0, 57344, 2);   // lvl5
    __syncthreads();
    stage_w(3);
    __syncthreads();
    tree_level(smb, lane, wave, 0,    8192, 5, 2, 8, 24576, 0, 57344, 6);   // lvl6
    __syncthreads();
    stage_w(4);
    __syncthreads();
    tree_level(smb, lane, wave, 8192, 0,    4, 3, 8, 24576, 0, 57344, 14);  // lvl7 -> A8 flat @P0
    __syncthreads();
    stage_w(5);
    __syncthreads();
    // lvl8: 16 n7-planes x 8 bi rows; feat -> AF plain [n8l][bi][c] bf16
    {
        const int m = lane & 15, kg = lane >> 4;
        for (int at = wave; at < 16; at += 4) {
            s16x8 af = *(const s16x8*)(smb + at * 512 + fsw((uint)(m * 64 + kg * 16)));
#pragma unroll
            for (int sib = 0; sib < 2; sib++) {
                int nl = 2 * at + sib;
                s16x8 bf = *(const s16x8*)(smb + 24576 +
                             fsw((uint)(nl * 1024 + m * 64 + kg * 16)));
                float bv = *(const float*)(smb + 57344 + ((30 + nl) * 16 + m) * 4);
                f32x4 acc = {bv, bv, bv, bv};
                acc = __builtin_amdgcn_mfma_f32_16x16x32_bf16(af, bf, acc, 0, 0, 0);
                if (kg < 2) {
                    float v[4] = {fmaxf(acc.x, 0.f), fmaxf(acc.y, 0.f),
                                  fmaxf(acc.z, 0.f), fmaxf(acc.w, 0.f)};
#pragma unroll
                    for (int j = 0; j < 4; j++)
                        *(ushort*)(smb + 16384 + nl * 256 + (kg * 4 + j) * 32 + m * 2) = bfr(v[j]);
                }
            }
        }
    }
    __syncthreads();
    // AF -> S8[(n3*64+chunk)][n8l][bi][c], coalesced float4
    {
        float4* dst = (float4*)(S8 + (size_t)(n3 * 64 + chunk) * 8192);
        for (int ci = tid; ci < 512; ci += 256)
            dst[ci] = *(const float4*)(smb + 16384 + ci * 16);
    }
}

// Kernel C: dense 16->64 + complex recombine. block=(n8g, half) x 128 thr.
__global__ __launch_bounds__(128, 8)
void ibf_C(const float* __restrict__ fea_dense, const char* __restrict__ S8,
           float* __restrict__ out)
{
    __shared__ ushort FEb[1024];   // [u][c] bf16
    const int tid = threadIdx.x, lane = tid & 63, wave = tid >> 6;
    const int n8g = blockIdx.x, half = blockIdx.y;
    const int n3 = n8g >> 5, n8l = n8g & 31;

    for (int idx = tid; idx < 1024; idx += 128) {
        int c = idx >> 6, u = idx & 63;
        FEb[u * 16 + c] = bfr(fea_dense[(size_t)n8g * 1024 + idx]);
    }
    __syncthreads();

    const int m = lane & 15, kg = lane >> 4;
    s16x8 bfrg[4];
#pragma unroll
    for (int ut = 0; ut < 4; ut++) {
        if (kg < 2) bfrg[ut] = *(const s16x8*)(FEb + (ut * 16 + m) * 16 + kg * 8);
        else        bfrg[ut] = (s16x8){0, 0, 0, 0, 0, 0, 0, 0};
    }
    for (int w8 = 0; w8 < 8; w8++) {
        const int tile  = half * 16 + wave * 8 + w8;
        const int birow = tile * 16 + m;
        s16x8 af = {0, 0, 0, 0, 0, 0, 0, 0};
        if (kg < 2)
            af = *(const s16x8*)(S8 + ((size_t)(n3 * 64 + (birow >> 3)) * 32 + n8l) * 256
                                 + (birow & 7) * 32 + kg * 16);
        const int b0  = (tile * 16 + kg * 4) >> 1;
        const bool odd = (m & 1);
#pragma unroll
        for (int ut = 0; ut < 4; ut++) {
            f32x4 acc = {0.f, 0.f, 0.f, 0.f};
            acc = __builtin_amdgcn_mfma_f32_16x16x32_bf16(af, bfrg[ut], acc, 0, 0, 0);
            float sy = __shfl_xor(acc.y, 1);
            float sw = __shfl_xor(acc.w, 1);
            const int g = n8g * 32 + ut * 8 + (m >> 1);
            float v0 = odd ? acc.x : (acc.x - sy) * (1.f / 16384.f);
            float v1 = odd ? acc.z : (acc.z - sw) * (1.f / 16384.f);
            size_t off = (odd ? (size_t)OUT_HALF : (size_t)0) + (size_t)g;
            out[(size_t)b0 * 8192 + off]       = v0;
            out[(size_t)(b0 + 1) * 8192 + off] = v1;
        }
    }
}

extern "C" void kernel_launch(void* const* d_in, const int* in_sizes, int n_in,
                              void* d_out, int out_size, void* d_ws, size_t ws_size,
                              hipStream_t stream) {
    const float* in_data   = (const float*)d_in[0];
    const float* mid_dense = (const float*)d_in[1];
    const float* in_filter = (const float*)d_in[2];
    const float* in_bias   = (const float*)d_in[3];
    const float* filters   = (const float*)d_in[4];
    const float* biases    = (const float*)d_in[5];
    const float* fea_dense = (const float*)d_in[6];
    float* out = (float*)d_out;
    uint* S3   = (uint*)d_ws;                        // 4 MB
    char* S8   = (char*)d_ws + (4 << 20);            // 4 MB

    ibf_A<<<dim3(256, 2), 256, 0, stream>>>(in_data, mid_dense, in_filter, in_bias,
                                            filters, biases, S3);
    ibf_B<<<dim3(8, 64), 256, 0, stream>>>(filters, biases, S3, S8);
    ibf_C<<<dim3(256, 2), 128, 0, stream>>>(fea_dense, S8, out);
}